// Round 1
// baseline (326.090 us; speedup 1.0000x reference)
//
#include <hip/hip_runtime.h>

// Problem constants (must match reference)
constexpr int   NRg = 1500;
constexpr int   NZg = 400;
constexpr float Hg      = 0.1f;
constexpr float RGRID0g = 0.0f;
constexpr float ZGRID0g = -5.0f;
constexpr float REG_DT  = 0.1f;

__global__ void zero_loss_kernel(float* loss) {
    *loss = 0.0f;
}

__global__ __launch_bounds__(256) void travel_time_kernel(
    const int*   __restrict__ station_index,
    const int*   __restrict__ event_index,
    const int*   __restrict__ phase_type,
    const float* __restrict__ phase_time,
    const float* __restrict__ phase_weight,
    const float* __restrict__ event_loc,      // [NUM_EVENT,3]
    const float* __restrict__ event_time,     // [NUM_EVENT,1]
    const float* __restrict__ station_loc,    // [NUM_STATION,3]
    const float* __restrict__ station_dt,     // [NUM_STATION,2]
    const float* __restrict__ timetable,      // [2, NR*NZ]
    float* __restrict__ out_t,                // [N]
    float* __restrict__ out_loss,             // [1]
    int n)
{
    const int i = blockIdx.x * blockDim.x + threadIdx.x;

    float acc = 0.0f;
    if (i < n) {
        const int s = station_index[i];
        const int e = event_index[i];
        const int p = phase_type[i];

        const float sx = station_loc[s * 3 + 0];
        const float sy = station_loc[s * 3 + 1];
        const float sz = station_loc[s * 3 + 2];
        const float ex = event_loc[e * 3 + 0];
        const float ey = event_loc[e * 3 + 1];
        const float ez = event_loc[e * 3 + 2];

        const float dx = ex - sx;
        const float dy = ey - sy;
        const float r  = sqrtf(dx * dx + dy * dy);
        const float z  = ez - sz;

        const float sdt   = station_dt[s * 2 + p];
        const float etime = event_time[e];

        // bilinear interpolation (match reference fp32 expression order)
        float fr = floorf((r - RGRID0g) / Hg);
        float fz = floorf((z - ZGRID0g) / Hg);
        fr = fminf(fmaxf(fr, 0.0f), (float)(NRg - 2));
        fz = fminf(fmaxf(fz, 0.0f), (float)(NZg - 2));
        const int ir0 = (int)fr;
        const int iz0 = (int)fz;

        const float x1 = (float)ir0 * Hg + RGRID0g;
        const float y1 = (float)iz0 * Hg + ZGRID0g;
        const float x2 = x1 + Hg;
        const float y2 = y1 + Hg;

        const int base = p * (NRg * NZg) + ir0 * NZg + iz0;
        const float Q11 = timetable[base];
        const float Q12 = timetable[base + 1];
        const float Q21 = timetable[base + NZg];
        const float Q22 = timetable[base + NZg + 1];

        const float tt = (Q11 * (x2 - r) * (y2 - z)
                        + Q21 * (r - x1) * (y2 - z)
                        + Q12 * (x2 - r) * (z - y1)
                        + Q22 * (r - x1) * (z - y1)) / (Hg * Hg);

        const float t = etime + tt + sdt;
        out_t[i] = t;

        const float err = t - phase_time[i];
        const float a   = fabsf(err);
        const float hub = (a < 1.0f) ? (0.5f * err * err) : (a - 0.5f);
        acc = hub * phase_weight[i] + REG_DT * fabsf(sdt);
    }

    // wave (64-lane) shuffle reduction
    #pragma unroll
    for (int off = 32; off > 0; off >>= 1)
        acc += __shfl_down(acc, off, 64);

    __shared__ float smem[4];  // 256 threads / 64 lanes = 4 waves
    const int lane = threadIdx.x & 63;
    const int wid  = threadIdx.x >> 6;
    if (lane == 0) smem[wid] = acc;
    __syncthreads();

    if (threadIdx.x == 0) {
        const float blocksum = smem[0] + smem[1] + smem[2] + smem[3];
        atomicAdd(out_loss, blocksum);
    }
}

extern "C" void kernel_launch(void* const* d_in, const int* in_sizes, int n_in,
                              void* d_out, int out_size, void* d_ws, size_t ws_size,
                              hipStream_t stream) {
    const int*   station_index = (const int*)  d_in[0];
    const int*   event_index   = (const int*)  d_in[1];
    const int*   phase_type    = (const int*)  d_in[2];
    const float* phase_time    = (const float*)d_in[3];
    const float* phase_weight  = (const float*)d_in[4];
    const float* event_loc     = (const float*)d_in[5];
    const float* event_time    = (const float*)d_in[6];
    const float* station_loc   = (const float*)d_in[7];
    const float* station_dt    = (const float*)d_in[8];
    const float* timetable     = (const float*)d_in[9];
    // d_in[10], d_in[11]: timetable gradients — unused by the forward reference

    const int n = in_sizes[0];
    float* out_t    = (float*)d_out;
    float* out_loss = (float*)d_out + n;

    zero_loss_kernel<<<1, 1, 0, stream>>>(out_loss);

    const int block = 256;
    const int grid  = (n + block - 1) / block;
    travel_time_kernel<<<grid, block, 0, stream>>>(
        station_index, event_index, phase_type, phase_time, phase_weight,
        event_loc, event_time, station_loc, station_dt, timetable,
        out_t, out_loss, n);
}

// Round 2
// 206.584 us; speedup vs baseline: 1.5785x; 1.5785x over previous
//
#include <hip/hip_runtime.h>

// Problem constants (must match reference)
constexpr int   NRg = 1500;
constexpr int   NZg = 400;
constexpr int   NCELL = NRg * NZg;          // 600000
constexpr int   NUM_EVENT_MAX   = 10000;
constexpr int   NUM_STATION_MAX = 1000;
constexpr float Hg      = 0.1f;
constexpr float RGRID0g = 0.0f;
constexpr float ZGRID0g = -5.0f;
constexpr float REG_DT  = 0.1f;

__global__ void zero_loss_kernel(float* loss) {
    *loss = 0.0f;
}

// st4[s*2+p] = {sx, sy, sz, station_dt[s][p]}  (2*NUM_STATION float4 = 32 KB)
__global__ __launch_bounds__(256) void pack_stations_kernel(
    const float* __restrict__ station_loc,   // [NS,3]
    const float* __restrict__ station_dt,    // [NS,2]
    float4* __restrict__ st4, int ns)
{
    int i = blockIdx.x * blockDim.x + threadIdx.x;   // i = s*2+p
    if (i < ns * 2) {
        int s = i >> 1;
        st4[i] = make_float4(station_loc[s * 3 + 0],
                             station_loc[s * 3 + 1],
                             station_loc[s * 3 + 2],
                             station_dt[i]);
    }
}

// ev4[e] = {ex, ey, ez, event_time[e]}  (NUM_EVENT float4 = 160 KB)
__global__ __launch_bounds__(256) void pack_events_kernel(
    const float* __restrict__ event_loc,     // [NE,3]
    const float* __restrict__ event_time,    // [NE,1]
    float4* __restrict__ ev4, int ne)
{
    int e = blockIdx.x * blockDim.x + threadIdx.x;
    if (e < ne) {
        ev4[e] = make_float4(event_loc[e * 3 + 0],
                             event_loc[e * 3 + 1],
                             event_loc[e * 3 + 2],
                             event_time[e]);
    }
}

// cell4[p*NCELL + ir*NZ + iz] = {Q11, Q12, Q21, Q22}  (2*NCELL float4 = 19.2 MB)
__global__ __launch_bounds__(256) void pack_table_kernel(
    const float* __restrict__ timetable,     // [2, NR*NZ]
    float4* __restrict__ cell4)
{
    int i = blockIdx.x * blockDim.x + threadIdx.x;   // over 2*NCELL
    if (i < 2 * NCELL) {
        int p  = i / NCELL;
        int c  = i - p * NCELL;
        int ir = c / NZg;
        int iz = c - ir * NZg;
        int irn = (ir + 1 < NRg) ? ir + 1 : ir;      // edge cells never used (ir0<=NR-2)
        int izn = (iz + 1 < NZg) ? iz + 1 : iz;
        int b  = p * NCELL;
        cell4[i] = make_float4(timetable[b + ir * NZg + iz],
                               timetable[b + ir * NZg + izn],
                               timetable[b + irn * NZg + iz],
                               timetable[b + irn * NZg + izn]);
    }
}

__device__ __forceinline__ float pick_body(
    int s, int e, int p, float ptime, float pweight,
    const float4* __restrict__ st4, const float4* __restrict__ ev4,
    const float4* __restrict__ cell4, float* __restrict__ t_out)
{
    const float4 st = st4[s * 2 + p];   // sx, sy, sz, sdt
    const float4 ev = ev4[e];           // ex, ey, ez, etime

    const float dx = ev.x - st.x;
    const float dy = ev.y - st.y;
    const float r  = sqrtf(dx * dx + dy * dy);
    const float z  = ev.z - st.z;

    float fr = floorf((r - RGRID0g) / Hg);
    float fz = floorf((z - ZGRID0g) / Hg);
    fr = fminf(fmaxf(fr, 0.0f), (float)(NRg - 2));
    fz = fminf(fmaxf(fz, 0.0f), (float)(NZg - 2));
    const int ir0 = (int)fr;
    const int iz0 = (int)fz;

    const float x1 = (float)ir0 * Hg + RGRID0g;
    const float y1 = (float)iz0 * Hg + ZGRID0g;
    const float x2 = x1 + Hg;
    const float y2 = y1 + Hg;

    const float4 Q = cell4[p * NCELL + ir0 * NZg + iz0]; // Q11,Q12,Q21,Q22

    const float tt = (Q.x * (x2 - r) * (y2 - z)
                    + Q.z * (r - x1) * (y2 - z)
                    + Q.y * (x2 - r) * (z - y1)
                    + Q.w * (r - x1) * (z - y1)) / (Hg * Hg);

    const float t = ev.w + tt + st.w;
    *t_out = t;

    const float err = t - ptime;
    const float a   = fabsf(err);
    const float hub = (a < 1.0f) ? (0.5f * err * err) : (a - 0.5f);
    return hub * pweight + REG_DT * fabsf(st.w);
}

// 4 picks per thread, vectorized stream loads, packed gathers.
__global__ __launch_bounds__(256) void travel_time_v2_kernel(
    const int4*   __restrict__ station_index4,
    const int4*   __restrict__ event_index4,
    const int4*   __restrict__ phase_type4,
    const float4* __restrict__ phase_time4,
    const float4* __restrict__ phase_weight4,
    const float4* __restrict__ st4,
    const float4* __restrict__ ev4,
    const float4* __restrict__ cell4,
    float4* __restrict__ out_t4,
    float*  __restrict__ out_loss,
    int n4)                                   // number of full groups of 4
{
    const int i = blockIdx.x * blockDim.x + threadIdx.x;

    float acc = 0.0f;
    if (i < n4) {
        const int4   si = station_index4[i];
        const int4   ei = event_index4[i];
        const int4   pi = phase_type4[i];
        const float4 pt = phase_time4[i];
        const float4 pw = phase_weight4[i];

        float4 t4;
        acc += pick_body(si.x, ei.x, pi.x, pt.x, pw.x, st4, ev4, cell4, &t4.x);
        acc += pick_body(si.y, ei.y, pi.y, pt.y, pw.y, st4, ev4, cell4, &t4.y);
        acc += pick_body(si.z, ei.z, pi.z, pt.z, pw.z, st4, ev4, cell4, &t4.z);
        acc += pick_body(si.w, ei.w, pi.w, pt.w, pw.w, st4, ev4, cell4, &t4.w);
        out_t4[i] = t4;
    }

    // wave (64-lane) shuffle reduction
    #pragma unroll
    for (int off = 32; off > 0; off >>= 1)
        acc += __shfl_down(acc, off, 64);

    __shared__ float smem[4];
    const int lane = threadIdx.x & 63;
    const int wid  = threadIdx.x >> 6;
    if (lane == 0) smem[wid] = acc;
    __syncthreads();

    if (threadIdx.x == 0) {
        atomicAdd(out_loss, smem[0] + smem[1] + smem[2] + smem[3]);
    }
}

// Scalar tail (n % 4 leftovers), also handles the loss for those picks.
__global__ __launch_bounds__(64) void travel_time_tail_kernel(
    const int*   __restrict__ station_index,
    const int*   __restrict__ event_index,
    const int*   __restrict__ phase_type,
    const float* __restrict__ phase_time,
    const float* __restrict__ phase_weight,
    const float4* __restrict__ st4,
    const float4* __restrict__ ev4,
    const float4* __restrict__ cell4,
    float* __restrict__ out_t,
    float* __restrict__ out_loss,
    int start, int n)
{
    const int i = start + blockIdx.x * blockDim.x + threadIdx.x;
    float acc = 0.0f;
    if (i < n) {
        float t;
        acc = pick_body(station_index[i], event_index[i], phase_type[i],
                        phase_time[i], phase_weight[i], st4, ev4, cell4, &t);
        out_t[i] = t;
    }
    #pragma unroll
    for (int off = 32; off > 0; off >>= 1)
        acc += __shfl_down(acc, off, 64);
    if ((threadIdx.x & 63) == 0 && acc != 0.0f)
        atomicAdd(out_loss, acc);
}

// Full fallback (round-1 kernel) in case ws_size is too small for packing.
__global__ __launch_bounds__(256) void travel_time_v1_kernel(
    const int*   __restrict__ station_index,
    const int*   __restrict__ event_index,
    const int*   __restrict__ phase_type,
    const float* __restrict__ phase_time,
    const float* __restrict__ phase_weight,
    const float* __restrict__ event_loc,
    const float* __restrict__ event_time,
    const float* __restrict__ station_loc,
    const float* __restrict__ station_dt,
    const float* __restrict__ timetable,
    float* __restrict__ out_t,
    float* __restrict__ out_loss,
    int n)
{
    const int i = blockIdx.x * blockDim.x + threadIdx.x;
    float acc = 0.0f;
    if (i < n) {
        const int s = station_index[i];
        const int e = event_index[i];
        const int p = phase_type[i];
        const float sx = station_loc[s * 3 + 0];
        const float sy = station_loc[s * 3 + 1];
        const float sz = station_loc[s * 3 + 2];
        const float ex = event_loc[e * 3 + 0];
        const float ey = event_loc[e * 3 + 1];
        const float ez = event_loc[e * 3 + 2];
        const float dx = ex - sx, dy = ey - sy;
        const float r = sqrtf(dx * dx + dy * dy);
        const float z = ez - sz;
        const float sdt = station_dt[s * 2 + p];
        const float etime = event_time[e];
        float fr = floorf((r - RGRID0g) / Hg);
        float fz = floorf((z - ZGRID0g) / Hg);
        fr = fminf(fmaxf(fr, 0.0f), (float)(NRg - 2));
        fz = fminf(fmaxf(fz, 0.0f), (float)(NZg - 2));
        const int ir0 = (int)fr, iz0 = (int)fz;
        const float x1 = (float)ir0 * Hg + RGRID0g;
        const float y1 = (float)iz0 * Hg + ZGRID0g;
        const float x2 = x1 + Hg, y2 = y1 + Hg;
        const int base = p * NCELL + ir0 * NZg + iz0;
        const float Q11 = timetable[base];
        const float Q12 = timetable[base + 1];
        const float Q21 = timetable[base + NZg];
        const float Q22 = timetable[base + NZg + 1];
        const float tt = (Q11 * (x2 - r) * (y2 - z) + Q21 * (r - x1) * (y2 - z)
                        + Q12 * (x2 - r) * (z - y1) + Q22 * (r - x1) * (z - y1)) / (Hg * Hg);
        const float t = etime + tt + sdt;
        out_t[i] = t;
        const float err = t - phase_time[i];
        const float a = fabsf(err);
        acc = ((a < 1.0f) ? (0.5f * err * err) : (a - 0.5f)) * phase_weight[i]
            + REG_DT * fabsf(sdt);
    }
    #pragma unroll
    for (int off = 32; off > 0; off >>= 1)
        acc += __shfl_down(acc, off, 64);
    __shared__ float smem[4];
    const int lane = threadIdx.x & 63, wid = threadIdx.x >> 6;
    if (lane == 0) smem[wid] = acc;
    __syncthreads();
    if (threadIdx.x == 0)
        atomicAdd(out_loss, smem[0] + smem[1] + smem[2] + smem[3]);
}

extern "C" void kernel_launch(void* const* d_in, const int* in_sizes, int n_in,
                              void* d_out, int out_size, void* d_ws, size_t ws_size,
                              hipStream_t stream) {
    const int*   station_index = (const int*)  d_in[0];
    const int*   event_index   = (const int*)  d_in[1];
    const int*   phase_type    = (const int*)  d_in[2];
    const float* phase_time    = (const float*)d_in[3];
    const float* phase_weight  = (const float*)d_in[4];
    const float* event_loc     = (const float*)d_in[5];
    const float* event_time    = (const float*)d_in[6];
    const float* station_loc   = (const float*)d_in[7];
    const float* station_dt    = (const float*)d_in[8];
    const float* timetable     = (const float*)d_in[9];

    const int n  = in_sizes[0];
    const int ns = in_sizes[7] / 3;      // NUM_STATION
    const int ne = in_sizes[5] / 3;      // NUM_EVENT

    float* out_t    = (float*)d_out;
    float* out_loss = (float*)d_out + n;

    zero_loss_kernel<<<1, 1, 0, stream>>>(out_loss);

    // Workspace layout: st4 | ev4 | cell4
    const size_t st4_bytes   = (size_t)ns * 2 * sizeof(float4);
    const size_t ev4_bytes   = (size_t)ne * sizeof(float4);
    const size_t cell4_bytes = (size_t)2 * NCELL * sizeof(float4);

    if (ws_size >= st4_bytes + ev4_bytes + cell4_bytes) {
        float4* st4   = (float4*)d_ws;
        float4* ev4   = (float4*)((char*)d_ws + st4_bytes);
        float4* cell4 = (float4*)((char*)d_ws + st4_bytes + ev4_bytes);

        pack_stations_kernel<<<(ns * 2 + 255) / 256, 256, 0, stream>>>(
            station_loc, station_dt, st4, ns);
        pack_events_kernel<<<(ne + 255) / 256, 256, 0, stream>>>(
            event_loc, event_time, ev4, ne);
        pack_table_kernel<<<(2 * NCELL + 255) / 256, 256, 0, stream>>>(
            timetable, cell4);

        const int n4 = n / 4;
        travel_time_v2_kernel<<<(n4 + 255) / 256, 256, 0, stream>>>(
            (const int4*)station_index, (const int4*)event_index,
            (const int4*)phase_type, (const float4*)phase_time,
            (const float4*)phase_weight, st4, ev4, cell4,
            (float4*)out_t, out_loss, n4);

        const int tail = n - n4 * 4;
        if (tail > 0) {
            travel_time_tail_kernel<<<(tail + 63) / 64, 64, 0, stream>>>(
                station_index, event_index, phase_type, phase_time, phase_weight,
                st4, ev4, cell4, out_t, out_loss, n4 * 4, n);
        }
    } else {
        travel_time_v1_kernel<<<(n + 255) / 256, 256, 0, stream>>>(
            station_index, event_index, phase_type, phase_time, phase_weight,
            event_loc, event_time, station_loc, station_dt, timetable,
            out_t, out_loss, n);
    }
}

// Round 5
// 195.199 us; speedup vs baseline: 1.6706x; 1.0583x over previous
//
#include <hip/hip_runtime.h>

// Problem constants (must match reference)
constexpr int   NRg = 1500;
constexpr int   NZg = 400;
constexpr int   NCELL = NRg * NZg;          // 600000
constexpr float Hg      = 0.1f;
constexpr float RGRID0g = 0.0f;
constexpr float ZGRID0g = -5.0f;
constexpr float REG_DT  = 0.1f;

constexpr int MAX_ST2 = 2048;               // max packed station entries (s*2+p) in LDS (32 KB)

// Native clang vector types (HIP_vector_type is rejected by nontemporal builtins)
typedef int   int4n   __attribute__((ext_vector_type(4)));
typedef float float4n __attribute__((ext_vector_type(4)));

struct PickResult { float t; float loss; };

__global__ void zero_loss_kernel(float* loss) {
    *loss = 0.0f;
}

// st4[s*2+p] = {sx, sy, sz, station_dt[s][p]}  (2*NUM_STATION float4 = 32 KB)
__global__ __launch_bounds__(256) void pack_stations_kernel(
    const float* __restrict__ station_loc,   // [NS,3]
    const float* __restrict__ station_dt,    // [NS,2]
    float4* __restrict__ st4, int ns)
{
    int i = blockIdx.x * blockDim.x + threadIdx.x;   // i = s*2+p
    if (i < ns * 2) {
        int s = i >> 1;
        st4[i] = make_float4(station_loc[s * 3 + 0],
                             station_loc[s * 3 + 1],
                             station_loc[s * 3 + 2],
                             station_dt[i]);
    }
}

// ev4[e] = {ex, ey, ez, event_time[e]}  (NUM_EVENT float4 = 160 KB)
__global__ __launch_bounds__(256) void pack_events_kernel(
    const float* __restrict__ event_loc,     // [NE,3]
    const float* __restrict__ event_time,    // [NE,1]
    float4* __restrict__ ev4, int ne)
{
    int e = blockIdx.x * blockDim.x + threadIdx.x;
    if (e < ne) {
        ev4[e] = make_float4(event_loc[e * 3 + 0],
                             event_loc[e * 3 + 1],
                             event_loc[e * 3 + 2],
                             event_time[e]);
    }
}

// Core per-pick math. st comes from LDS (or global in tail), ev from the packed
// L2-resident table, Q values as 4 dword gathers from the 4.8 MB timetable
// (cache-resident).
__device__ __forceinline__ PickResult pick_body(
    int s, int e, int p, float ptime, float pweight,
    const float4* __restrict__ st_tab, const float4* __restrict__ ev4,
    const float* __restrict__ tab)
{
    const float4 st = st_tab[s * 2 + p];   // sx, sy, sz, sdt
    const float4 ev = ev4[e];              // ex, ey, ez, etime

    const float dx = ev.x - st.x;
    const float dy = ev.y - st.y;
    const float r  = sqrtf(dx * dx + dy * dy);
    const float z  = ev.z - st.z;

    float fr = floorf((r - RGRID0g) / Hg);
    float fz = floorf((z - ZGRID0g) / Hg);
    fr = fminf(fmaxf(fr, 0.0f), (float)(NRg - 2));
    fz = fminf(fmaxf(fz, 0.0f), (float)(NZg - 2));
    const int ir0 = (int)fr;
    const int iz0 = (int)fz;

    const float x1 = (float)ir0 * Hg + RGRID0g;
    const float y1 = (float)iz0 * Hg + ZGRID0g;
    const float x2 = x1 + Hg;
    const float y2 = y1 + Hg;

    const int base = p * NCELL + ir0 * NZg + iz0;
    const float Q11 = tab[base];
    const float Q12 = tab[base + 1];
    const float Q21 = tab[base + NZg];
    const float Q22 = tab[base + NZg + 1];

    const float tt = (Q11 * (x2 - r) * (y2 - z)
                    + Q21 * (r - x1) * (y2 - z)
                    + Q12 * (x2 - r) * (z - y1)
                    + Q22 * (r - x1) * (z - y1)) / (Hg * Hg);

    PickResult res;
    res.t = ev.w + tt + st.w;

    const float err = res.t - ptime;
    const float a   = fabsf(err);
    const float hub = (a < 1.0f) ? (0.5f * err * err) : (a - 0.5f);
    res.loss = hub * pweight + REG_DT * fabsf(st.w);
    return res;
}

// One float4-group (4 picks) with non-temporal stream access.
__device__ __forceinline__ float do_group(
    int g,
    const int4n*   __restrict__ si4, const int4n* __restrict__ ei4,
    const int4n*   __restrict__ pi4,
    const float4n* __restrict__ pt4, const float4n* __restrict__ pw4,
    const float4*  __restrict__ st_tab, const float4* __restrict__ ev4,
    const float*   __restrict__ tab, float4n* __restrict__ out_t4)
{
    const int4n   si = __builtin_nontemporal_load(&si4[g]);
    const int4n   ei = __builtin_nontemporal_load(&ei4[g]);
    const int4n   pi = __builtin_nontemporal_load(&pi4[g]);
    const float4n pt = __builtin_nontemporal_load(&pt4[g]);
    const float4n pw = __builtin_nontemporal_load(&pw4[g]);

    const PickResult r0 = pick_body(si.x, ei.x, pi.x, pt.x, pw.x, st_tab, ev4, tab);
    const PickResult r1 = pick_body(si.y, ei.y, pi.y, pt.y, pw.y, st_tab, ev4, tab);
    const PickResult r2 = pick_body(si.z, ei.z, pi.z, pt.z, pw.z, st_tab, ev4, tab);
    const PickResult r3 = pick_body(si.w, ei.w, pi.w, pt.w, pw.w, st_tab, ev4, tab);

    float4n t4;
    t4.x = r0.t; t4.y = r1.t; t4.z = r2.t; t4.w = r3.t;
    __builtin_nontemporal_store(t4, &out_t4[g]);
    return r0.loss + r1.loss + r2.loss + r3.loss;
}

// 8 picks per thread (groups i and i+T), stations staged in LDS.
__global__ __launch_bounds__(256) void travel_time_v3_kernel(
    const int4n*   __restrict__ si4,
    const int4n*   __restrict__ ei4,
    const int4n*   __restrict__ pi4,
    const float4n* __restrict__ pt4,
    const float4n* __restrict__ pw4,
    const float4*  __restrict__ st4,
    const float4*  __restrict__ ev4,
    const float*   __restrict__ tab,
    float4n* __restrict__ out_t4,
    float*   __restrict__ out_loss,
    int ns2, int T)
{
    __shared__ float4 sh_st[MAX_ST2];
    for (int j = threadIdx.x; j < ns2; j += 256)
        sh_st[j] = st4[j];
    __syncthreads();

    const int i = blockIdx.x * blockDim.x + threadIdx.x;

    float acc = 0.0f;
    if (i < T) {
        acc += do_group(i,     si4, ei4, pi4, pt4, pw4, sh_st, ev4, tab, out_t4);
        acc += do_group(i + T, si4, ei4, pi4, pt4, pw4, sh_st, ev4, tab, out_t4);
    }

    // wave (64-lane) shuffle reduction
    #pragma unroll
    for (int off = 32; off > 0; off >>= 1)
        acc += __shfl_down(acc, off, 64);

    __shared__ float smem[4];
    const int lane = threadIdx.x & 63;
    const int wid  = threadIdx.x >> 6;
    if (lane == 0) smem[wid] = acc;
    __syncthreads();

    if (threadIdx.x == 0)
        atomicAdd(out_loss, smem[0] + smem[1] + smem[2] + smem[3]);
}

// Scalar tail for picks in [start, n) not covered by the main kernel.
__global__ __launch_bounds__(64) void travel_time_tail_kernel(
    const int*   __restrict__ station_index,
    const int*   __restrict__ event_index,
    const int*   __restrict__ phase_type,
    const float* __restrict__ phase_time,
    const float* __restrict__ phase_weight,
    const float4* __restrict__ st4,
    const float4* __restrict__ ev4,
    const float*  __restrict__ tab,
    float* __restrict__ out_t,
    float* __restrict__ out_loss,
    int start, int n)
{
    const int i = start + blockIdx.x * blockDim.x + threadIdx.x;
    float acc = 0.0f;
    if (i < n) {
        const PickResult r = pick_body(station_index[i], event_index[i], phase_type[i],
                                       phase_time[i], phase_weight[i], st4, ev4, tab);
        out_t[i] = r.t;
        acc = r.loss;
    }
    #pragma unroll
    for (int off = 32; off > 0; off >>= 1)
        acc += __shfl_down(acc, off, 64);
    if ((threadIdx.x & 63) == 0 && acc != 0.0f)
        atomicAdd(out_loss, acc);
}

// Full fallback (round-1 kernel) in case ws_size is too small for packing.
__global__ __launch_bounds__(256) void travel_time_v1_kernel(
    const int*   __restrict__ station_index,
    const int*   __restrict__ event_index,
    const int*   __restrict__ phase_type,
    const float* __restrict__ phase_time,
    const float* __restrict__ phase_weight,
    const float* __restrict__ event_loc,
    const float* __restrict__ event_time,
    const float* __restrict__ station_loc,
    const float* __restrict__ station_dt,
    const float* __restrict__ timetable,
    float* __restrict__ out_t,
    float* __restrict__ out_loss,
    int n)
{
    const int i = blockIdx.x * blockDim.x + threadIdx.x;
    float acc = 0.0f;
    if (i < n) {
        const int s = station_index[i];
        const int e = event_index[i];
        const int p = phase_type[i];
        const float sx = station_loc[s * 3 + 0];
        const float sy = station_loc[s * 3 + 1];
        const float sz = station_loc[s * 3 + 2];
        const float ex = event_loc[e * 3 + 0];
        const float ey = event_loc[e * 3 + 1];
        const float ez = event_loc[e * 3 + 2];
        const float dx = ex - sx, dy = ey - sy;
        const float r = sqrtf(dx * dx + dy * dy);
        const float z = ez - sz;
        const float sdt = station_dt[s * 2 + p];
        const float etime = event_time[e];
        float fr = floorf((r - RGRID0g) / Hg);
        float fz = floorf((z - ZGRID0g) / Hg);
        fr = fminf(fmaxf(fr, 0.0f), (float)(NRg - 2));
        fz = fminf(fmaxf(fz, 0.0f), (float)(NZg - 2));
        const int ir0 = (int)fr, iz0 = (int)fz;
        const float x1 = (float)ir0 * Hg + RGRID0g;
        const float y1 = (float)iz0 * Hg + ZGRID0g;
        const float x2 = x1 + Hg, y2 = y1 + Hg;
        const int base = p * NCELL + ir0 * NZg + iz0;
        const float Q11 = timetable[base];
        const float Q12 = timetable[base + 1];
        const float Q21 = timetable[base + NZg];
        const float Q22 = timetable[base + NZg + 1];
        const float tt = (Q11 * (x2 - r) * (y2 - z) + Q21 * (r - x1) * (y2 - z)
                        + Q12 * (x2 - r) * (z - y1) + Q22 * (r - x1) * (z - y1)) / (Hg * Hg);
        const float t = etime + tt + sdt;
        out_t[i] = t;
        const float err = t - phase_time[i];
        const float a = fabsf(err);
        acc = ((a < 1.0f) ? (0.5f * err * err) : (a - 0.5f)) * phase_weight[i]
            + REG_DT * fabsf(sdt);
    }
    #pragma unroll
    for (int off = 32; off > 0; off >>= 1)
        acc += __shfl_down(acc, off, 64);
    __shared__ float smem[4];
    const int lane = threadIdx.x & 63, wid = threadIdx.x >> 6;
    if (lane == 0) smem[wid] = acc;
    __syncthreads();
    if (threadIdx.x == 0)
        atomicAdd(out_loss, smem[0] + smem[1] + smem[2] + smem[3]);
}

extern "C" void kernel_launch(void* const* d_in, const int* in_sizes, int n_in,
                              void* d_out, int out_size, void* d_ws, size_t ws_size,
                              hipStream_t stream) {
    const int*   station_index = (const int*)  d_in[0];
    const int*   event_index   = (const int*)  d_in[1];
    const int*   phase_type    = (const int*)  d_in[2];
    const float* phase_time    = (const float*)d_in[3];
    const float* phase_weight  = (const float*)d_in[4];
    const float* event_loc     = (const float*)d_in[5];
    const float* event_time    = (const float*)d_in[6];
    const float* station_loc   = (const float*)d_in[7];
    const float* station_dt    = (const float*)d_in[8];
    const float* timetable     = (const float*)d_in[9];

    const int n  = in_sizes[0];
    const int ns = in_sizes[7] / 3;      // NUM_STATION
    const int ne = in_sizes[5] / 3;      // NUM_EVENT
    const int ns2 = ns * 2;

    float* out_t    = (float*)d_out;
    float* out_loss = (float*)d_out + n;

    zero_loss_kernel<<<1, 1, 0, stream>>>(out_loss);

    // Workspace layout: st4 | ev4  (no big cell table)
    const size_t st4_bytes = (size_t)ns2 * sizeof(float4);
    const size_t ev4_bytes = (size_t)ne * sizeof(float4);

    if (ws_size >= st4_bytes + ev4_bytes && ns2 <= MAX_ST2) {
        float4* st4 = (float4*)d_ws;
        float4* ev4 = (float4*)((char*)d_ws + st4_bytes);

        pack_stations_kernel<<<(ns2 + 255) / 256, 256, 0, stream>>>(
            station_loc, station_dt, st4, ns);
        pack_events_kernel<<<(ne + 255) / 256, 256, 0, stream>>>(
            event_loc, event_time, ev4, ne);

        const int n4 = n / 4;        // full float4 groups
        const int T  = n4 / 2;       // threads in main kernel; each does groups i, i+T
        if (T > 0) {
            travel_time_v3_kernel<<<(T + 255) / 256, 256, 0, stream>>>(
                (const int4n*)station_index, (const int4n*)event_index,
                (const int4n*)phase_type, (const float4n*)phase_time,
                (const float4n*)phase_weight, st4, ev4, timetable,
                (float4n*)out_t, out_loss, ns2, T);
        }
        const int covered = T * 8;   // 2T groups × 4 picks
        if (covered < n) {
            const int tail = n - covered;
            travel_time_tail_kernel<<<(tail + 63) / 64, 64, 0, stream>>>(
                station_index, event_index, phase_type, phase_time, phase_weight,
                st4, ev4, timetable, out_t, out_loss, covered, n);
        }
    } else {
        travel_time_v1_kernel<<<(n + 255) / 256, 256, 0, stream>>>(
            station_index, event_index, phase_type, phase_time, phase_weight,
            event_loc, event_time, station_loc, station_dt, timetable,
            out_t, out_loss, n);
    }
}